// Round 3
// baseline (431.888 us; speedup 1.0000x reference)
//
#include <hip/hip_runtime.h>
#include <math.h>

#define NBLEND 24
#define HDIM 128
#define KHALF 64
#define MAX_STEPS 10
#define CVG_T 1e-5f
#define DVG_T 1.0f
#define EPS_B 1e-6f

typedef float v2f __attribute__((ext_vector_type(2)));

#if __has_builtin(__builtin_elementwise_fma)
#define VFMA(a, b, c) __builtin_elementwise_fma((a), (b), (c))
#else
static __device__ __forceinline__ v2f VFMA(v2f a, v2f b, v2f c) {
    v2f r; r.x = fmaf(a.x, b.x, c.x); r.y = fmaf(a.y, b.y, c.y); return r;
}
#endif

__device__ __forceinline__ float softplus_f(float x) {
    // jax.nn.softplus: max(x,0) + log1p(exp(-|x|)), numerically stable
    float e = __expf(-fabsf(x));
    return fmaxf(x, 0.0f) + __logf(1.0f + e);
}

// One g(x) evaluation, split across a wave PAIR: wave (2i) handles k-half 0,
// wave (2i+1) handles k-half 1, for the same 64 points. Weight addresses stay
// wave-uniform (scalar loads). Partial logits combined via LDS.
// Both waves produce bit-identical g (float add is commutative).
__device__ __forceinline__ void eval_g_pair(
    v2f (&part)[4][NBLEND / 2][64],
    int w, int half, int lane,
    const float* __restrict__ W0, const float* __restrict__ b0,
    const float* __restrict__ W1, const float* __restrict__ b1,
    const float* __restrict__ W2, const float* __restrict__ b2,
    const float* __restrict__ tfs,
    float x0, float x1, float x2,
    float xd0, float xd1, float xd2,
    float& g0, float& g1, float& g2)
{
    v2f acc[KHALF / 2];
    {
        const v2f* __restrict__ b1v = (const v2f*)(b1 + half * KHALF);
        #pragma unroll
        for (int kk = 0; kk < KHALF / 2; ++kk) acc[kk] = b1v[kk];
    }
    const float* __restrict__ W1h = W1 + half * KHALF;
    v2f vx0 = {x0, x0}, vx1 = {x1, x1}, vx2 = {x2, x2};

    #pragma unroll 2
    for (int j = 0; j < HDIM; j += 2) {
        v2f z = *(const v2f*)(b0 + j);
        z = VFMA(vx0, *(const v2f*)(W0 + j), z);
        z = VFMA(vx1, *(const v2f*)(W0 + HDIM + j), z);
        z = VFMA(vx2, *(const v2f*)(W0 + 2 * HDIM + j), z);
        float ha = softplus_f(z.x);
        float hb = softplus_f(z.y);
        const v2f* __restrict__ r0 = (const v2f*)(W1h + j * HDIM);
        const v2f* __restrict__ r1 = (const v2f*)(W1h + (j + 1) * HDIM);
        v2f hva = {ha, ha}, hvb = {hb, hb};
        #pragma unroll
        for (int kk = 0; kk < KHALF / 2; ++kk) acc[kk] = VFMA(hva, r0[kk], acc[kk]);
        #pragma unroll
        for (int kk = 0; kk < KHALF / 2; ++kk) acc[kk] = VFMA(hvb, r1[kk], acc[kk]);
    }
    #pragma unroll
    for (int kk = 0; kk < KHALF / 2; ++kk) {
        acc[kk].x = softplus_f(acc[kk].x);
        acc[kk].y = softplus_f(acc[kk].y);
    }

    // partial logits over own k-half (b2 added once, by half 0)
    v2f lg[NBLEND / 2];
    if (half == 0) {
        const v2f* __restrict__ b2v = (const v2f*)b2;
        #pragma unroll
        for (int m2 = 0; m2 < NBLEND / 2; ++m2) lg[m2] = b2v[m2];
    } else {
        #pragma unroll
        for (int m2 = 0; m2 < NBLEND / 2; ++m2) lg[m2] = (v2f){0.f, 0.f};
    }
    const float* __restrict__ W2h = W2 + half * KHALF * NBLEND;
    #pragma unroll
    for (int kk = 0; kk < KHALF; ++kk) {
        float h1 = (kk & 1) ? acc[kk >> 1].y : acc[kk >> 1].x;
        v2f hv = {h1, h1};
        const v2f* __restrict__ w2r = (const v2f*)(W2h + kk * NBLEND);
        #pragma unroll
        for (int m2 = 0; m2 < NBLEND / 2; ++m2) lg[m2] = VFMA(hv, w2r[m2], lg[m2]);
    }

    // exchange partials with the partner wave
    #pragma unroll
    for (int m2 = 0; m2 < NBLEND / 2; ++m2) part[w][m2][lane] = lg[m2];
    __syncthreads();
    #pragma unroll
    for (int m2 = 0; m2 < NBLEND / 2; ++m2) lg[m2] += part[w ^ 1][m2][lane];

    // online softmax over 24 logits, accumulating blended 3x4 transform T
    float M = -3.0e38f, S = 0.f;
    v2f T[6];
    #pragma unroll
    for (int t = 0; t < 6; ++t) T[t] = (v2f){0.f, 0.f};
    #pragma unroll
    for (int m = 0; m < NBLEND; ++m) {
        float lgm = (m & 1) ? lg[m >> 1].y : lg[m >> 1].x;
        float Mn = fmaxf(M, lgm);
        float c = __expf(M - Mn);
        float e = __expf(lgm - Mn);
        S = fmaf(S, c, e);
        const v2f* __restrict__ tf = (const v2f*)(tfs + m * 12);
        v2f cv = {c, c}, ev = {e, e};
        #pragma unroll
        for (int t = 0; t < 6; ++t) T[t] = VFMA(T[t], cv, ev * tf[t]);
        M = Mn;
    }
    float inv = 1.0f / S;
    g0 = inv * fmaf(T[0].x, x0, fmaf(T[0].y, x1, fmaf(T[1].x, x2, T[1].y))) - xd0;
    g1 = inv * fmaf(T[2].x, x0, fmaf(T[2].y, x1, fmaf(T[3].x, x2, T[3].y))) - xd1;
    g2 = inv * fmaf(T[4].x, x0, fmaf(T[4].y, x1, fmaf(T[5].x, x2, T[5].y))) - xd2;
}

__global__ void __launch_bounds__(256, 4)
broyden_kernel(const float* __restrict__ xd_p,
               const float* __restrict__ x_init,
               const float* __restrict__ Jinv_init,
               const float* __restrict__ tfs,
               const float* __restrict__ W0, const float* __restrict__ b0,
               const float* __restrict__ W1, const float* __restrict__ b1,
               const float* __restrict__ W2, const float* __restrict__ b2,
               float* __restrict__ out, int N)
{
    __shared__ v2f part[4][NBLEND / 2][64];
    __shared__ int s_any;

    const int tid = threadIdx.x;
    const int lane = tid & 63;
    const int w = __builtin_amdgcn_readfirstlane(tid >> 6);   // wave id: SGPR
    const int half = w & 1;
    const int n0 = blockIdx.x * 128 + (w >> 1) * 64 + lane;   // point index
    const int n = (n0 < N) ? n0 : (N - 1);

    float xd0 = xd_p[n * 3 + 0], xd1 = xd_p[n * 3 + 1], xd2 = xd_p[n * 3 + 2];
    float x0 = x_init[n * 3 + 0], x1 = x_init[n * 3 + 1], x2 = x_init[n * 3 + 2];
    float J0 = Jinv_init[n * 9 + 0], J1 = Jinv_init[n * 9 + 1], J2 = Jinv_init[n * 9 + 2];
    float J3 = Jinv_init[n * 9 + 3], J4 = Jinv_init[n * 9 + 4], J5 = Jinv_init[n * 9 + 5];
    float J6 = Jinv_init[n * 9 + 6], J7 = Jinv_init[n * 9 + 7], J8 = Jinv_init[n * 9 + 8];

    float g0, g1, g2;
    eval_g_pair(part, w, half, lane, W0, b0, W1, b1, W2, b2, tfs,
                x0, x1, x2, xd0, xd1, xd2, g0, g1, g2);

    float u0 = -(fmaf(J0, g0, fmaf(J1, g1, J2 * g2)));
    float u1 = -(fmaf(J3, g0, fmaf(J4, g1, J5 * g2)));
    float u2 = -(fmaf(J6, g0, fmaf(J7, g1, J8 * g2)));

    float gn_opt = sqrtf(g0 * g0 + g1 * g1 + g2 * g2);
    float xo0 = x0, xo1 = x1, xo2 = x2;
    bool ids = true;   // reference initializes ids = ones(bool)

    for (int step = 0; step < MAX_STEPS; ++step) {
        // block-uniform early exit (manual syncthreads_or)
        if (tid == 0) s_any = 0;
        __syncthreads();                 // also protects LDS part[] WAR
        if (ids) s_any = 1;
        __syncthreads();
        if (!s_any) break;

        // masked step: inactive lanes take dx=0 -> dg==0 exactly -> state frozen
        float dx0 = ids ? u0 : 0.f, dx1 = ids ? u1 : 0.f, dx2 = ids ? u2 : 0.f;
        x0 += dx0; x1 += dx1; x2 += dx2;

        float ng0, ng1, ng2;
        eval_g_pair(part, w, half, lane, W0, b0, W1, b1, W2, b2, tfs,
                    x0, x1, x2, xd0, xd1, xd2, ng0, ng1, ng2);
        float dg0 = ng0 - g0, dg1 = ng1 - g1, dg2 = ng2 - g2;
        g0 = ng0; g1 = ng1; g2 = ng2;

        float gn = sqrtf(g0 * g0 + g1 * g1 + g2 * g2);
        bool better = gn < gn_opt;              // false for NaN (matches jnp.where)
        if (better) { gn_opt = gn; xo0 = x0; xo1 = x1; xo2 = x2; }
        bool ids_new = (gn_opt > CVG_T) && (gn < DVG_T);

        float vT0 = fmaf(dx0, J0, fmaf(dx1, J3, dx2 * J6));
        float vT1 = fmaf(dx0, J1, fmaf(dx1, J4, dx2 * J7));
        float vT2 = fmaf(dx0, J2, fmaf(dx1, J5, dx2 * J8));
        float a0 = dx0 - fmaf(J0, dg0, fmaf(J1, dg1, J2 * dg2));
        float a1 = dx1 - fmaf(J3, dg0, fmaf(J4, dg1, J5 * dg2));
        float a2 = dx2 - fmaf(J6, dg0, fmaf(J7, dg1, J8 * dg2));
        float bb = fmaf(vT0, dg0, fmaf(vT1, dg1, vT2 * dg2));
        bb += (bb >= 0.f) ? EPS_B : -EPS_B;
        // select (NOT multiply) so NaN iu can't leak into J when masked off
        float iu0 = ids_new ? (a0 / bb) : 0.f;
        float iu1 = ids_new ? (a1 / bb) : 0.f;
        float iu2 = ids_new ? (a2 / bb) : 0.f;
        J0 = fmaf(iu0, vT0, J0); J1 = fmaf(iu0, vT1, J1); J2 = fmaf(iu0, vT2, J2);
        J3 = fmaf(iu1, vT0, J3); J4 = fmaf(iu1, vT1, J4); J5 = fmaf(iu1, vT2, J5);
        J6 = fmaf(iu2, vT0, J6); J7 = fmaf(iu2, vT1, J7); J8 = fmaf(iu2, vT2, J8);

        u0 = -(fmaf(J0, g0, fmaf(J1, g1, J2 * g2)));
        u1 = -(fmaf(J3, g0, fmaf(J4, g1, J5 * g2)));
        u2 = -(fmaf(J6, g0, fmaf(J7, g1, J8 * g2)));
        ids = ids_new;
    }

    // outputs: x_opt (N,3,1) | gn_opt (N) | valid (N) as 0.0/1.0
    if (half == 0 && n0 < N) {
        out[n * 3 + 0] = xo0;
        out[n * 3 + 1] = xo1;
        out[n * 3 + 2] = xo2;
        out[3 * N + n] = gn_opt;
        out[4 * N + n] = (gn_opt < CVG_T) ? 1.0f : 0.0f;
    }
}

extern "C" void kernel_launch(void* const* d_in, const int* in_sizes, int n_in,
                              void* d_out, int out_size, void* d_ws, size_t ws_size,
                              hipStream_t stream) {
    const float* xd     = (const float*)d_in[0];
    const float* x_init = (const float*)d_in[1];
    const float* Jinv   = (const float*)d_in[2];
    const float* tfs    = (const float*)d_in[3];
    const float* W0     = (const float*)d_in[4];
    const float* b0     = (const float*)d_in[5];
    const float* W1     = (const float*)d_in[6];
    const float* b1     = (const float*)d_in[7];
    const float* W2     = (const float*)d_in[8];
    const float* b2     = (const float*)d_in[9];
    float* out = (float*)d_out;

    const int N = in_sizes[0] / 3;
    dim3 block(256);
    dim3 grid((N + 127) / 128);   // 2 waves per 64 points

    hipLaunchKernelGGL(broyden_kernel, grid, block, 0, stream,
                       xd, x_init, Jinv, tfs, W0, b0, W1, b1, W2, b2, out, N);
}

// Round 4
// 391.855 us; speedup vs baseline: 1.1022x; 1.1022x over previous
//
#include <hip/hip_runtime.h>
#include <math.h>

#define NBLEND 24
#define HDIM 128
#define KHALF 64
#define MAX_STEPS 10
#define CVG_T 1e-5f
#define DVG_T 1.0f
#define EPS_B 1e-6f

typedef float v2f __attribute__((ext_vector_type(2)));

#if __has_builtin(__builtin_elementwise_fma)
#define VFMA(a, b, c) __builtin_elementwise_fma((a), (b), (c))
#else
static __device__ __forceinline__ v2f VFMA(v2f a, v2f b, v2f c) {
    v2f r; r.x = fmaf(a.x, b.x, c.x); r.y = fmaf(a.y, b.y, c.y); return r;
}
#endif

__device__ __forceinline__ float softplus_f(float x) {
    // jax.nn.softplus: max(x,0) + log1p(exp(-|x|)), numerically stable
    float e = __expf(-fabsf(x));
    return fmaxf(x, 0.0f) + __logf(1.0f + e);
}

// One g(x) evaluation, split across a wave PAIR: wave (2i) handles k-half 0,
// wave (2i+1) handles k-half 1, for the same 64 points. Weight addresses stay
// wave-uniform (scalar loads). Partial logits combined via LDS.
// Both waves produce bit-identical g (float add is commutative).
__device__ __forceinline__ void eval_g_pair(
    v2f (&part)[4][NBLEND / 2][64],
    int w, int half, int lane,
    const float* __restrict__ W0, const float* __restrict__ b0,
    const float* __restrict__ W1, const float* __restrict__ b1,
    const float* __restrict__ W2, const float* __restrict__ b2,
    const float* __restrict__ tfs,
    float x0, float x1, float x2,
    float xd0, float xd1, float xd2,
    float& g0, float& g1, float& g2)
{
    v2f acc[KHALF / 2];
    {
        const v2f* __restrict__ b1v = (const v2f*)(b1 + half * KHALF);
        #pragma unroll
        for (int kk = 0; kk < KHALF / 2; ++kk) acc[kk] = b1v[kk];
    }
    const float* __restrict__ W1h = W1 + half * KHALF;
    v2f vx0 = {x0, x0}, vx1 = {x1, x1}, vx2 = {x2, x2};

    #pragma unroll 2
    for (int j = 0; j < HDIM; j += 2) {
        v2f z = *(const v2f*)(b0 + j);
        z = VFMA(vx0, *(const v2f*)(W0 + j), z);
        z = VFMA(vx1, *(const v2f*)(W0 + HDIM + j), z);
        z = VFMA(vx2, *(const v2f*)(W0 + 2 * HDIM + j), z);
        float ha = softplus_f(z.x);
        float hb = softplus_f(z.y);
        const v2f* __restrict__ r0 = (const v2f*)(W1h + j * HDIM);
        const v2f* __restrict__ r1 = (const v2f*)(W1h + (j + 1) * HDIM);
        v2f hva = {ha, ha}, hvb = {hb, hb};
        #pragma unroll
        for (int kk = 0; kk < KHALF / 2; ++kk) acc[kk] = VFMA(hva, r0[kk], acc[kk]);
        #pragma unroll
        for (int kk = 0; kk < KHALF / 2; ++kk) acc[kk] = VFMA(hvb, r1[kk], acc[kk]);
    }
    #pragma unroll
    for (int kk = 0; kk < KHALF / 2; ++kk) {
        acc[kk].x = softplus_f(acc[kk].x);
        acc[kk].y = softplus_f(acc[kk].y);
    }

    // partial logits over own k-half (b2 added once, by half 0)
    v2f lg[NBLEND / 2];
    if (half == 0) {
        const v2f* __restrict__ b2v = (const v2f*)b2;
        #pragma unroll
        for (int m2 = 0; m2 < NBLEND / 2; ++m2) lg[m2] = b2v[m2];
    } else {
        #pragma unroll
        for (int m2 = 0; m2 < NBLEND / 2; ++m2) lg[m2] = (v2f){0.f, 0.f};
    }
    const float* __restrict__ W2h = W2 + half * KHALF * NBLEND;
    #pragma unroll
    for (int kk = 0; kk < KHALF; ++kk) {
        float h1 = (kk & 1) ? acc[kk >> 1].y : acc[kk >> 1].x;
        v2f hv = {h1, h1};
        const v2f* __restrict__ w2r = (const v2f*)(W2h + kk * NBLEND);
        #pragma unroll
        for (int m2 = 0; m2 < NBLEND / 2; ++m2) lg[m2] = VFMA(hv, w2r[m2], lg[m2]);
    }

    // exchange partials with the partner wave
    #pragma unroll
    for (int m2 = 0; m2 < NBLEND / 2; ++m2) part[w][m2][lane] = lg[m2];
    __syncthreads();
    #pragma unroll
    for (int m2 = 0; m2 < NBLEND / 2; ++m2) lg[m2] += part[w ^ 1][m2][lane];

    // two-pass softmax over 24 logits (matches jax.nn.softmax: exp(l-max)/sum)
    float M = -3.0e38f;
    #pragma unroll
    for (int m2 = 0; m2 < NBLEND / 2; ++m2)
        M = fmaxf(M, fmaxf(lg[m2].x, lg[m2].y));

    float S = 0.f;
    v2f T[6];
    #pragma unroll
    for (int t = 0; t < 6; ++t) T[t] = (v2f){0.f, 0.f};
    #pragma unroll
    for (int m = 0; m < NBLEND; ++m) {
        float lgm = (m & 1) ? lg[m >> 1].y : lg[m >> 1].x;
        float e = __expf(lgm - M);
        S += e;
        const v2f* __restrict__ tf = (const v2f*)(tfs + m * 12);
        v2f ev = {e, e};
        #pragma unroll
        for (int t = 0; t < 6; ++t) T[t] = VFMA(ev, tf[t], T[t]);
    }
    float inv = 1.0f / S;
    g0 = inv * fmaf(T[0].x, x0, fmaf(T[0].y, x1, fmaf(T[1].x, x2, T[1].y))) - xd0;
    g1 = inv * fmaf(T[2].x, x0, fmaf(T[2].y, x1, fmaf(T[3].x, x2, T[3].y))) - xd1;
    g2 = inv * fmaf(T[4].x, x0, fmaf(T[4].y, x1, fmaf(T[5].x, x2, T[5].y))) - xd2;
}

__global__ void __launch_bounds__(256, 2)
broyden_kernel(const float* __restrict__ xd_p,
               const float* __restrict__ x_init,
               const float* __restrict__ Jinv_init,
               const float* __restrict__ tfs,
               const float* __restrict__ W0, const float* __restrict__ b0,
               const float* __restrict__ W1, const float* __restrict__ b1,
               const float* __restrict__ W2, const float* __restrict__ b2,
               float* __restrict__ out, int N)
{
    __shared__ v2f part[4][NBLEND / 2][64];
    __shared__ int s_any;

    const int tid = threadIdx.x;
    const int lane = tid & 63;
    const int w = __builtin_amdgcn_readfirstlane(tid >> 6);   // wave id: SGPR
    const int half = w & 1;
    const int n0 = blockIdx.x * 128 + (w >> 1) * 64 + lane;   // point index
    const int n = (n0 < N) ? n0 : (N - 1);

    float xd0 = xd_p[n * 3 + 0], xd1 = xd_p[n * 3 + 1], xd2 = xd_p[n * 3 + 2];
    float x0 = x_init[n * 3 + 0], x1 = x_init[n * 3 + 1], x2 = x_init[n * 3 + 2];
    float J0 = Jinv_init[n * 9 + 0], J1 = Jinv_init[n * 9 + 1], J2 = Jinv_init[n * 9 + 2];
    float J3 = Jinv_init[n * 9 + 3], J4 = Jinv_init[n * 9 + 4], J5 = Jinv_init[n * 9 + 5];
    float J6 = Jinv_init[n * 9 + 6], J7 = Jinv_init[n * 9 + 7], J8 = Jinv_init[n * 9 + 8];

    float g0, g1, g2;
    eval_g_pair(part, w, half, lane, W0, b0, W1, b1, W2, b2, tfs,
                x0, x1, x2, xd0, xd1, xd2, g0, g1, g2);

    float u0 = -(fmaf(J0, g0, fmaf(J1, g1, J2 * g2)));
    float u1 = -(fmaf(J3, g0, fmaf(J4, g1, J5 * g2)));
    float u2 = -(fmaf(J6, g0, fmaf(J7, g1, J8 * g2)));

    float gn_opt = sqrtf(g0 * g0 + g1 * g1 + g2 * g2);
    float xo0 = x0, xo1 = x1, xo2 = x2;
    bool ids = true;   // reference initializes ids = ones(bool)

    for (int step = 0; step < MAX_STEPS; ++step) {
        // block-uniform early exit (manual syncthreads_or)
        if (tid == 0) s_any = 0;
        __syncthreads();                 // also protects LDS part[] WAR
        if (ids) s_any = 1;
        __syncthreads();
        if (!s_any) break;

        // masked step: inactive lanes take dx=0 -> dg==0 exactly -> state frozen
        float dx0 = ids ? u0 : 0.f, dx1 = ids ? u1 : 0.f, dx2 = ids ? u2 : 0.f;
        x0 += dx0; x1 += dx1; x2 += dx2;

        float ng0, ng1, ng2;
        eval_g_pair(part, w, half, lane, W0, b0, W1, b1, W2, b2, tfs,
                    x0, x1, x2, xd0, xd1, xd2, ng0, ng1, ng2);
        float dg0 = ng0 - g0, dg1 = ng1 - g1, dg2 = ng2 - g2;
        g0 = ng0; g1 = ng1; g2 = ng2;

        float gn = sqrtf(g0 * g0 + g1 * g1 + g2 * g2);
        bool better = gn < gn_opt;              // false for NaN (matches jnp.where)
        if (better) { gn_opt = gn; xo0 = x0; xo1 = x1; xo2 = x2; }
        bool ids_new = (gn_opt > CVG_T) && (gn < DVG_T);

        float vT0 = fmaf(dx0, J0, fmaf(dx1, J3, dx2 * J6));
        float vT1 = fmaf(dx0, J1, fmaf(dx1, J4, dx2 * J7));
        float vT2 = fmaf(dx0, J2, fmaf(dx1, J5, dx2 * J8));
        float a0 = dx0 - fmaf(J0, dg0, fmaf(J1, dg1, J2 * dg2));
        float a1 = dx1 - fmaf(J3, dg0, fmaf(J4, dg1, J5 * dg2));
        float a2 = dx2 - fmaf(J6, dg0, fmaf(J7, dg1, J8 * dg2));
        float bb = fmaf(vT0, dg0, fmaf(vT1, dg1, vT2 * dg2));
        bb += (bb >= 0.f) ? EPS_B : -EPS_B;
        // select (NOT multiply) so NaN iu can't leak into J when masked off
        float iu0 = ids_new ? (a0 / bb) : 0.f;
        float iu1 = ids_new ? (a1 / bb) : 0.f;
        float iu2 = ids_new ? (a2 / bb) : 0.f;
        J0 = fmaf(iu0, vT0, J0); J1 = fmaf(iu0, vT1, J1); J2 = fmaf(iu0, vT2, J2);
        J3 = fmaf(iu1, vT0, J3); J4 = fmaf(iu1, vT1, J4); J5 = fmaf(iu1, vT2, J5);
        J6 = fmaf(iu2, vT0, J6); J7 = fmaf(iu2, vT1, J7); J8 = fmaf(iu2, vT2, J8);

        u0 = -(fmaf(J0, g0, fmaf(J1, g1, J2 * g2)));
        u1 = -(fmaf(J3, g0, fmaf(J4, g1, J5 * g2)));
        u2 = -(fmaf(J6, g0, fmaf(J7, g1, J8 * g2)));
        ids = ids_new;
    }

    // outputs: x_opt (N,3,1) | gn_opt (N) | valid (N) as 0.0/1.0
    if (half == 0 && n0 < N) {
        out[n * 3 + 0] = xo0;
        out[n * 3 + 1] = xo1;
        out[n * 3 + 2] = xo2;
        out[3 * N + n] = gn_opt;
        out[4 * N + n] = (gn_opt < CVG_T) ? 1.0f : 0.0f;
    }
}

extern "C" void kernel_launch(void* const* d_in, const int* in_sizes, int n_in,
                              void* d_out, int out_size, void* d_ws, size_t ws_size,
                              hipStream_t stream) {
    const float* xd     = (const float*)d_in[0];
    const float* x_init = (const float*)d_in[1];
    const float* Jinv   = (const float*)d_in[2];
    const float* tfs    = (const float*)d_in[3];
    const float* W0     = (const float*)d_in[4];
    const float* b0     = (const float*)d_in[5];
    const float* W1     = (const float*)d_in[6];
    const float* b1     = (const float*)d_in[7];
    const float* W2     = (const float*)d_in[8];
    const float* b2     = (const float*)d_in[9];
    float* out = (float*)d_out;

    const int N = in_sizes[0] / 3;
    dim3 block(256);
    dim3 grid((N + 127) / 128);   // 2 waves per 64 points

    hipLaunchKernelGGL(broyden_kernel, grid, block, 0, stream,
                       xd, x_init, Jinv, tfs, W0, b0, W1, b1, W2, b2, out, N);
}

// Round 5
// 387.139 us; speedup vs baseline: 1.1156x; 1.0122x over previous
//
#include <hip/hip_runtime.h>
#include <math.h>

#define NBLEND 24
#define HDIM 128
#define KHALF 64
#define MAX_STEPS 10
#define CVG_T 1e-5f
#define DVG_T 1.0f
#define EPS_B 1e-6f

typedef float v2f __attribute__((ext_vector_type(2)));

#if __has_builtin(__builtin_elementwise_fma)
#define VFMA(a, b, c) __builtin_elementwise_fma((a), (b), (c))
#else
static __device__ __forceinline__ v2f VFMA(v2f a, v2f b, v2f c) {
    v2f r; r.x = fmaf(a.x, b.x, c.x); r.y = fmaf(a.y, b.y, c.y); return r;
}
#endif

__device__ __forceinline__ float softplus_f(float x) {
    // jax.nn.softplus: max(x,0) + log1p(exp(-|x|)), numerically stable
    float e = __expf(-fabsf(x));
    return fmaxf(x, 0.0f) + __logf(1.0f + e);
}

// One g(x) evaluation, split across the block's wave PAIR: wave 0 handles
// k in [0,64), wave 1 handles k in [64,128), same 64 points (one per lane).
// Weight addresses are wave-uniform -> scalar loads. Partial logits combined
// via LDS; both waves then hold identical full logits and compute identical g.
__device__ __forceinline__ void eval_g_pair(
    v2f (&part)[2][NBLEND / 2][64],
    int w, int lane,
    const float* __restrict__ W0, const float* __restrict__ b0,
    const float* __restrict__ W1, const float* __restrict__ b1,
    const float* __restrict__ W2, const float* __restrict__ b2,
    const float* __restrict__ tfs,
    float x0, float x1, float x2,
    float xd0, float xd1, float xd2,
    float& g0, float& g1, float& g2)
{
    v2f acc[KHALF / 2];
    {
        const v2f* __restrict__ b1v = (const v2f*)(b1 + w * KHALF);
        #pragma unroll
        for (int kk = 0; kk < KHALF / 2; ++kk) acc[kk] = b1v[kk];
    }
    const float* __restrict__ W1h = W1 + w * KHALF;
    v2f vx0 = {x0, x0}, vx1 = {x1, x1}, vx2 = {x2, x2};

    #pragma unroll 2
    for (int j = 0; j < HDIM; j += 2) {
        v2f z = *(const v2f*)(b0 + j);
        z = VFMA(vx0, *(const v2f*)(W0 + j), z);
        z = VFMA(vx1, *(const v2f*)(W0 + HDIM + j), z);
        z = VFMA(vx2, *(const v2f*)(W0 + 2 * HDIM + j), z);
        float ha = softplus_f(z.x);
        float hb = softplus_f(z.y);
        const v2f* __restrict__ r0 = (const v2f*)(W1h + j * HDIM);
        const v2f* __restrict__ r1 = (const v2f*)(W1h + (j + 1) * HDIM);
        v2f hva = {ha, ha}, hvb = {hb, hb};
        #pragma unroll
        for (int kk = 0; kk < KHALF / 2; ++kk) acc[kk] = VFMA(hva, r0[kk], acc[kk]);
        #pragma unroll
        for (int kk = 0; kk < KHALF / 2; ++kk) acc[kk] = VFMA(hvb, r1[kk], acc[kk]);
    }
    #pragma unroll
    for (int kk = 0; kk < KHALF / 2; ++kk) {
        acc[kk].x = softplus_f(acc[kk].x);
        acc[kk].y = softplus_f(acc[kk].y);
    }

    // partial logits over own k-half (b2 added once, by wave 0)
    v2f lg[NBLEND / 2];
    if (w == 0) {
        const v2f* __restrict__ b2v = (const v2f*)b2;
        #pragma unroll
        for (int m2 = 0; m2 < NBLEND / 2; ++m2) lg[m2] = b2v[m2];
    } else {
        #pragma unroll
        for (int m2 = 0; m2 < NBLEND / 2; ++m2) lg[m2] = (v2f){0.f, 0.f};
    }
    const float* __restrict__ W2h = W2 + w * KHALF * NBLEND;
    #pragma unroll
    for (int kk = 0; kk < KHALF; ++kk) {
        float h1 = (kk & 1) ? acc[kk >> 1].y : acc[kk >> 1].x;
        v2f hv = {h1, h1};
        const v2f* __restrict__ w2r = (const v2f*)(W2h + kk * NBLEND);
        #pragma unroll
        for (int m2 = 0; m2 < NBLEND / 2; ++m2) lg[m2] = VFMA(hv, w2r[m2], lg[m2]);
    }

    // exchange partials with the partner wave
    #pragma unroll
    for (int m2 = 0; m2 < NBLEND / 2; ++m2) part[w][m2][lane] = lg[m2];
    __syncthreads();
    #pragma unroll
    for (int m2 = 0; m2 < NBLEND / 2; ++m2) lg[m2] += part[w ^ 1][m2][lane];

    // two-pass softmax over 24 logits (matches jax.nn.softmax: exp(l-max)/sum)
    float M = -3.0e38f;
    #pragma unroll
    for (int m2 = 0; m2 < NBLEND / 2; ++m2)
        M = fmaxf(M, fmaxf(lg[m2].x, lg[m2].y));

    float S = 0.f;
    v2f T[6];
    #pragma unroll
    for (int t = 0; t < 6; ++t) T[t] = (v2f){0.f, 0.f};
    #pragma unroll
    for (int m = 0; m < NBLEND; ++m) {
        float lgm = (m & 1) ? lg[m >> 1].y : lg[m >> 1].x;
        float e = __expf(lgm - M);
        S += e;
        const v2f* __restrict__ tf = (const v2f*)(tfs + m * 12);
        v2f ev = {e, e};
        #pragma unroll
        for (int t = 0; t < 6; ++t) T[t] = VFMA(ev, tf[t], T[t]);
    }
    float inv = 1.0f / S;
    g0 = inv * fmaf(T[0].x, x0, fmaf(T[0].y, x1, fmaf(T[1].x, x2, T[1].y))) - xd0;
    g1 = inv * fmaf(T[2].x, x0, fmaf(T[2].y, x1, fmaf(T[3].x, x2, T[3].y))) - xd1;
    g2 = inv * fmaf(T[4].x, x0, fmaf(T[4].y, x1, fmaf(T[5].x, x2, T[5].y))) - xd2;
}

__global__ void __launch_bounds__(128, 4)
broyden_kernel(const float* __restrict__ xd_p,
               const float* __restrict__ x_init,
               const float* __restrict__ Jinv_init,
               const float* __restrict__ tfs,
               const float* __restrict__ W0, const float* __restrict__ b0,
               const float* __restrict__ W1, const float* __restrict__ b1,
               const float* __restrict__ W2, const float* __restrict__ b2,
               float* __restrict__ out, int N)
{
    __shared__ v2f part[2][NBLEND / 2][64];

    const int tid = threadIdx.x;
    const int lane = tid & 63;
    const int w = __builtin_amdgcn_readfirstlane(tid >> 6);   // 0 or 1
    const int n = blockIdx.x * 64 + lane;                     // point (always < N)

    float xd0 = xd_p[n * 3 + 0], xd1 = xd_p[n * 3 + 1], xd2 = xd_p[n * 3 + 2];
    float x0 = x_init[n * 3 + 0], x1 = x_init[n * 3 + 1], x2 = x_init[n * 3 + 2];
    float J0 = Jinv_init[n * 9 + 0], J1 = Jinv_init[n * 9 + 1], J2 = Jinv_init[n * 9 + 2];
    float J3 = Jinv_init[n * 9 + 3], J4 = Jinv_init[n * 9 + 4], J5 = Jinv_init[n * 9 + 5];
    float J6 = Jinv_init[n * 9 + 6], J7 = Jinv_init[n * 9 + 7], J8 = Jinv_init[n * 9 + 8];

    float g0, g1, g2;
    eval_g_pair(part, w, lane, W0, b0, W1, b1, W2, b2, tfs,
                x0, x1, x2, xd0, xd1, xd2, g0, g1, g2);

    float u0 = -(fmaf(J0, g0, fmaf(J1, g1, J2 * g2)));
    float u1 = -(fmaf(J3, g0, fmaf(J4, g1, J5 * g2)));
    float u2 = -(fmaf(J6, g0, fmaf(J7, g1, J8 * g2)));

    float gn_opt = sqrtf(g0 * g0 + g1 * g1 + g2 * g2);
    float xo0 = x0, xo1 = x1, xo2 = x2;
    bool ids = true;   // reference initializes ids = ones(bool)

    for (int step = 0; step < MAX_STEPS; ++step) {
        // Both waves hold identical per-lane ids -> identical ballot -> the
        // break is pair-uniform; barriers stay aligned.
        if (__ballot(ids) == 0ull) break;
        __syncthreads();   // WAR: previous eval's part[] reads complete

        // masked step: inactive lanes take dx=0 -> dg==0 exactly -> state frozen
        float dx0 = ids ? u0 : 0.f, dx1 = ids ? u1 : 0.f, dx2 = ids ? u2 : 0.f;
        x0 += dx0; x1 += dx1; x2 += dx2;

        float ng0, ng1, ng2;
        eval_g_pair(part, w, lane, W0, b0, W1, b1, W2, b2, tfs,
                    x0, x1, x2, xd0, xd1, xd2, ng0, ng1, ng2);
        float dg0 = ng0 - g0, dg1 = ng1 - g1, dg2 = ng2 - g2;
        g0 = ng0; g1 = ng1; g2 = ng2;

        float gn = sqrtf(g0 * g0 + g1 * g1 + g2 * g2);
        bool better = gn < gn_opt;              // false for NaN (matches jnp.where)
        if (better) { gn_opt = gn; xo0 = x0; xo1 = x1; xo2 = x2; }
        bool ids_new = (gn_opt > CVG_T) && (gn < DVG_T);

        float vT0 = fmaf(dx0, J0, fmaf(dx1, J3, dx2 * J6));
        float vT1 = fmaf(dx0, J1, fmaf(dx1, J4, dx2 * J7));
        float vT2 = fmaf(dx0, J2, fmaf(dx1, J5, dx2 * J8));
        float a0 = dx0 - fmaf(J0, dg0, fmaf(J1, dg1, J2 * dg2));
        float a1 = dx1 - fmaf(J3, dg0, fmaf(J4, dg1, J5 * dg2));
        float a2 = dx2 - fmaf(J6, dg0, fmaf(J7, dg1, J8 * dg2));
        float bb = fmaf(vT0, dg0, fmaf(vT1, dg1, vT2 * dg2));
        bb += (bb >= 0.f) ? EPS_B : -EPS_B;
        // select (NOT multiply) so NaN iu can't leak into J when masked off
        float iu0 = ids_new ? (a0 / bb) : 0.f;
        float iu1 = ids_new ? (a1 / bb) : 0.f;
        float iu2 = ids_new ? (a2 / bb) : 0.f;
        J0 = fmaf(iu0, vT0, J0); J1 = fmaf(iu0, vT1, J1); J2 = fmaf(iu0, vT2, J2);
        J3 = fmaf(iu1, vT0, J3); J4 = fmaf(iu1, vT1, J4); J5 = fmaf(iu1, vT2, J5);
        J6 = fmaf(iu2, vT0, J6); J7 = fmaf(iu2, vT1, J7); J8 = fmaf(iu2, vT2, J8);

        u0 = -(fmaf(J0, g0, fmaf(J1, g1, J2 * g2)));
        u1 = -(fmaf(J3, g0, fmaf(J4, g1, J5 * g2)));
        u2 = -(fmaf(J6, g0, fmaf(J7, g1, J8 * g2)));
        ids = ids_new;
    }

    // outputs: x_opt (N,3,1) | gn_opt (N) | valid (N) as 0.0/1.0
    if (w == 0) {
        out[n * 3 + 0] = xo0;
        out[n * 3 + 1] = xo1;
        out[n * 3 + 2] = xo2;
        out[3 * N + n] = gn_opt;
        out[4 * N + n] = (gn_opt < CVG_T) ? 1.0f : 0.0f;
    }
}

extern "C" void kernel_launch(void* const* d_in, const int* in_sizes, int n_in,
                              void* d_out, int out_size, void* d_ws, size_t ws_size,
                              hipStream_t stream) {
    const float* xd     = (const float*)d_in[0];
    const float* x_init = (const float*)d_in[1];
    const float* Jinv   = (const float*)d_in[2];
    const float* tfs    = (const float*)d_in[3];
    const float* W0     = (const float*)d_in[4];
    const float* b0     = (const float*)d_in[5];
    const float* W1     = (const float*)d_in[6];
    const float* b1     = (const float*)d_in[7];
    const float* W2     = (const float*)d_in[8];
    const float* b2     = (const float*)d_in[9];
    float* out = (float*)d_out;

    const int N = in_sizes[0] / 3;
    dim3 block(128);
    dim3 grid((N + 63) / 64);   // one 64-point group (2 waves) per block

    hipLaunchKernelGGL(broyden_kernel, grid, block, 0, stream,
                       xd, x_init, Jinv, tfs, W0, b0, W1, b1, W2, b2, out, N);
}